// Round 2
// baseline (394.606 us; speedup 1.0000x reference)
//
#include <hip/hip_runtime.h>

#define D_IN   2048
#define D_OUT  2048
#define N_TOK  1024
#define N_B    8
#define RANK   16
#define TPB    8          // tokens per block
// SCALING = ALPHA/RANK = 16/16 = 1.0 -> omitted

__device__ __forceinline__ float dot4(float4 a, float4 b) {
    return a.x * b.x + a.y * b.y + a.z * b.z + a.w * b.w;
}

// v + dpp_shuffle(v); CTRL is a compile-time DPP control code.
template <int CTRL>
__device__ __forceinline__ float dpp_add(float v) {
    int s = __builtin_amdgcn_update_dpp(0, __float_as_int(v), CTRL, 0xF, 0xF, true);
    return v + __int_as_float(s);
}

// Full 64-lane sum: quad_perm xor1, xor2; row_ror 4, 8 (covers 16-lane row);
// then cross-row via shfl_xor 16 / 32. DPP steps run on the VALU pipe (no DS).
__device__ __forceinline__ float wave_sum(float v) {
    v = dpp_add<0xB1>(v);    // quad_perm [1,0,3,2]  : + lane^1
    v = dpp_add<0x4E>(v);    // quad_perm [2,3,0,1]  : + lane^2
    v = dpp_add<0x124>(v);   // row_ror:4            : + other quads
    v = dpp_add<0x128>(v);   // row_ror:8
    v += __shfl_xor(v, 16, 64);
    v += __shfl_xor(v, 32, 64);
    return v;
}

__global__ __launch_bounds__(256, 4)
void lora_fused_v2(const float* __restrict__ x,
                   const float* __restrict__ A,
                   const float* __restrict__ B,
                   const int* __restrict__ ids,
                   float* __restrict__ out) {
    __shared__ __align__(16) float bxs[TPB][RANK];   // 512 B handoff

    const int b    = blockIdx.y;
    const int tok0 = blockIdx.x * TPB;
    const int aid  = ids[b];
    const int tid  = threadIdx.x;
    const int wave = tid >> 6;          // 0..3 -> rank slice r0 = wave*4
    const int lane = tid & 63;

    const float* __restrict__ xb = x + ((size_t)b * N_TOK + tok0) * D_IN;
    const float* __restrict__ Ba = B + (size_t)aid * RANK * D_IN + (size_t)(wave * 4) * D_IN;
    const float* __restrict__ Aa = A + (size_t)aid * D_OUT * RANK;
    float* __restrict__ ob = out + ((size_t)b * N_TOK + tok0) * D_OUT;

    // ---------------- step 1: partial dots, lane splits i ----------------
    float acc[TPB][4];
    #pragma unroll
    for (int t = 0; t < TPB; ++t)
        #pragma unroll
        for (int r = 0; r < 4; ++r) acc[t][r] = 0.f;

    #pragma unroll
    for (int tile = 0; tile < 4; ++tile) {
        #pragma unroll
        for (int it = 0; it < 2; ++it) {
            const int ib = tile * 512 + it * 256 + lane * 4;
            const float4 b0 = *reinterpret_cast<const float4*>(&Ba[0 * D_IN + ib]);
            const float4 b1 = *reinterpret_cast<const float4*>(&Ba[1 * D_IN + ib]);
            const float4 b2 = *reinterpret_cast<const float4*>(&Ba[2 * D_IN + ib]);
            const float4 b3 = *reinterpret_cast<const float4*>(&Ba[3 * D_IN + ib]);
            #pragma unroll
            for (int t = 0; t < TPB; ++t) {
                const float4 xv = *reinterpret_cast<const float4*>(&xb[(size_t)t * D_IN + ib]);
                acc[t][0] += dot4(xv, b0);
                acc[t][1] += dot4(xv, b1);
                acc[t][2] += dot4(xv, b2);
                acc[t][3] += dot4(xv, b3);
            }
        }
    }

    // ---------------- wave-reduce 32 values, DPP-based ----------------
    #pragma unroll
    for (int t = 0; t < TPB; ++t)
        #pragma unroll
        for (int r = 0; r < 4; ++r)
            acc[t][r] = wave_sum(acc[t][r]);

    if (lane == 0) {
        #pragma unroll
        for (int t = 0; t < TPB; ++t)
            *reinterpret_cast<float4*>(&bxs[t][wave * 4]) =
                make_float4(acc[t][0], acc[t][1], acc[t][2], acc[t][3]);
    }
    __syncthreads();

    // ---------------- step 2: out[t][o] = sum_r bx[t][r] * A[o][r] ----------------
    // thread covers o0 = half*1024 + tid*4, 4 rows of A in regs per half
    #pragma unroll
    for (int half = 0; half < 2; ++half) {
        const int o0 = half * 1024 + tid * 4;
        float4 Ar[4][4];
        #pragma unroll
        for (int j = 0; j < 4; ++j)
            #pragma unroll
            for (int q = 0; q < 4; ++q)
                Ar[j][q] = *reinterpret_cast<const float4*>(&Aa[(size_t)(o0 + j) * RANK + q * 4]);

        #pragma unroll
        for (int t = 0; t < TPB; ++t) {
            const float4 p0 = *reinterpret_cast<const float4*>(&bxs[t][0]);
            const float4 p1 = *reinterpret_cast<const float4*>(&bxs[t][4]);
            const float4 p2 = *reinterpret_cast<const float4*>(&bxs[t][8]);
            const float4 p3 = *reinterpret_cast<const float4*>(&bxs[t][12]);
            float4 res;
            res.x = dot4(Ar[0][0], p0) + dot4(Ar[0][1], p1) + dot4(Ar[0][2], p2) + dot4(Ar[0][3], p3);
            res.y = dot4(Ar[1][0], p0) + dot4(Ar[1][1], p1) + dot4(Ar[1][2], p2) + dot4(Ar[1][3], p3);
            res.z = dot4(Ar[2][0], p0) + dot4(Ar[2][1], p1) + dot4(Ar[2][2], p2) + dot4(Ar[2][3], p3);
            res.w = dot4(Ar[3][0], p0) + dot4(Ar[3][1], p1) + dot4(Ar[3][2], p2) + dot4(Ar[3][3], p3);
            *reinterpret_cast<float4*>(&ob[(size_t)t * D_OUT + o0]) = res;
        }
    }
}

extern "C" void kernel_launch(void* const* d_in, const int* in_sizes, int n_in,
                              void* d_out, int out_size, void* d_ws, size_t ws_size,
                              hipStream_t stream) {
    const float* x   = (const float*)d_in[0];
    const float* A   = (const float*)d_in[1];
    const float* B   = (const float*)d_in[2];
    const int*   ids = (const int*)d_in[3];
    float* out = (float*)d_out;

    dim3 grid(N_TOK / TPB, N_B);   // (128, 8) = 1024 blocks, 4 per CU
    lora_fused_v2<<<grid, 256, 0, stream>>>(x, A, B, ids, out);
}